// Round 1
// baseline (393.248 us; speedup 1.0000x reference)
//
#include <hip/hip_runtime.h>

// ConvDeepSet: out[m,b,r] = bias[r] + sum_c v[b,m,c] * W[r,c]
//   v[b,m,0]   = dens = sum_n K(b,n,m)
//   v[b,m,1+j] = (sum_n co[n,b,j] * K(b,n,m)) / (dens + 1e-8)
//   K = exp(-0.5*(x[n,b]-y[m,b])^2 / ls^2)
//
// Sizes fixed by the reference:
#define N_CTX 2048
#define BATCH 16
#define M_TGT 4096
#define COUT  64
#define CCH   65     // Cout+1 (density channel prepended)
#define RDIM  128

#define TN     128   // n-tile staged in LDS
#define MTILE  64    // m per block
#define SPLIT  4     // threads per m splitting N (within a lane-quad)
#define NITER  (TN / SPLIT)
#define CO_STRIDE 68 // pad 64->68: 4 n-groups per wave land on disjoint bank quads; 272B keeps float4 alignment
#define V_STRIDE  68 // 272B rows -> float4-aligned

__global__ __launch_bounds__(256)
void convdeepset_kernel(const float* __restrict__ ci,    // (N,B,1)
                        const float* __restrict__ co,    // (N,B,64)
                        const float* __restrict__ ti,    // (M,B,1)
                        const float* __restrict__ ls,    // (1,)
                        const float* __restrict__ W,     // (128,65) row-major
                        const float* __restrict__ bias,  // (128,)
                        float* __restrict__ out)         // (M,B,128)
{
    __shared__ float co_tile[TN * CO_STRIDE];   // 34816 B; reused as W overlay in phase 2
    __shared__ float x_tile[TN];                //   512 B
    __shared__ float v_lds[MTILE * V_STRIDE];   // 17408 B
    // total 52736 B -> 3 blocks/CU

    const int tid     = threadIdx.x;
    const int b       = blockIdx.x & (BATCH - 1);
    const int mtile   = blockIdx.x >> 4;          // grid = 16 * (M/MTILE)
    const int m_local = tid >> 2;                 // 0..63
    const int split   = tid & 3;                  // quad split over N
    const int m_glob  = mtile * MTILE + m_local;

    const float y   = ti[(size_t)m_glob * BATCH + b];
    const float lsv = ls[0];
    const float fc  = -0.5f / (lsv * lsv);

    float acc[CCH];
#pragma unroll
    for (int c = 0; c < CCH; ++c) acc[c] = 0.0f;

    for (int t0 = 0; t0 < N_CTX; t0 += TN) {
        __syncthreads();  // protect co_tile/x_tile from previous tile's readers
        // ---- stage: co tile (TN x 64) and x tile, coalesced float4 ----
        {
            const int c4  = (tid & 15) << 2;   // 0,4,...,60
            const int nof = tid >> 4;          // 0..15
#pragma unroll
            for (int p = 0; p < TN / 16; ++p) {
                const int nl = p * 16 + nof;
                const int ng = t0 + nl;
                const float4 v = *(const float4*)(co + ((size_t)ng * BATCH + b) * COUT + c4);
                *(float4*)(co_tile + nl * CO_STRIDE + c4) = v;
            }
            if (tid < TN) x_tile[tid] = ci[(size_t)(t0 + tid) * BATCH + b];
        }
        __syncthreads();

        // ---- main: each thread covers n = i*4 + split within the tile ----
        for (int i = 0; i < NITER; ++i) {
            const int nl  = (i << 2) | split;
            const float x = x_tile[nl];
            const float d = x - y;
            const float K = __expf(fc * d * d);
            acc[0] += K;
            const float* cr = co_tile + nl * CO_STRIDE;
#pragma unroll
            for (int c = 0; c < COUT; c += 4) {
                const float4 cv = *(const float4*)(cr + c);
                acc[1 + c + 0] += K * cv.x;
                acc[1 + c + 1] += K * cv.y;
                acc[1 + c + 2] += K * cv.z;
                acc[1 + c + 3] += K * cv.w;
            }
        }
    }

    // ---- quad reduction over the N-split ----
#pragma unroll
    for (int c = 0; c < CCH; ++c) {
        acc[c] += __shfl_xor(acc[c], 1);
        acc[c] += __shfl_xor(acc[c], 2);
    }
    if (split == 0) {
        const float dens = acc[0];
        const float inv  = 1.0f / (dens + 1e-8f);
        float* vr = v_lds + m_local * V_STRIDE;
        vr[0] = dens;
#pragma unroll
        for (int c = 1; c < CCH; ++c) vr[c] = acc[c] * inv;
    }
    __syncthreads();

    // ---- stage W (128x65 = 8320 floats, contiguous) into co_tile overlay ----
    for (int idx = tid; idx < (RDIM * CCH) / 4; idx += 256)
        *(float4*)(co_tile + idx * 4) = *(const float4*)(W + idx * 4);
    __syncthreads();

    // ---- projection: thread = (r, m-half); W row in registers; v broadcast ----
    const int r      = tid & (RDIM - 1);
    const int m_half = tid >> 7;    // wave-uniform
    float w[CCH];
#pragma unroll
    for (int c = 0; c < CCH; ++c) w[c] = co_tile[r * CCH + c];
    const float br = bias[r];

    for (int mi = 0; mi < MTILE / 2; ++mi) {
        const int ml = m_half * (MTILE / 2) + mi;   // wave-uniform -> v reads broadcast
        const float* vr = v_lds + ml * V_STRIDE;
        float s0 = br, s1 = 0.0f, s2 = 0.0f, s3 = 0.0f;
#pragma unroll
        for (int c = 0; c < COUT; c += 4) {
            const float4 vv = *(const float4*)(vr + c);
            s0 += w[c + 0] * vv.x;
            s1 += w[c + 1] * vv.y;
            s2 += w[c + 2] * vv.z;
            s3 += w[c + 3] * vv.w;
        }
        s0 += w[COUT] * vr[COUT];   // density channel (c=64)
        const float val = (s0 + s1) + (s2 + s3);
        const int mg = mtile * MTILE + ml;
        out[((size_t)mg * BATCH + b) * RDIM + r] = val;
    }
}

extern "C" void kernel_launch(void* const* d_in, const int* in_sizes, int n_in,
                              void* d_out, int out_size, void* d_ws, size_t ws_size,
                              hipStream_t stream) {
    const float* ci   = (const float*)d_in[0];  // context_in  (N,B,1)
    const float* co   = (const float*)d_in[1];  // context_out (N,B,64)
    const float* ti   = (const float*)d_in[2];  // target_in   (M,B,1)
    const float* ls   = (const float*)d_in[3];  // lengthscale (1,)
    const float* W    = (const float*)d_in[4];  // (128,65)
    const float* bias = (const float*)d_in[5];  // (128,)
    float* o = (float*)d_out;                   // (M,B,128)

    const int grid = BATCH * (M_TGT / MTILE);   // 16 * 64 = 1024 blocks
    convdeepset_kernel<<<grid, 256, 0, stream>>>(ci, co, ti, ls, W, bias, o);
}

// Round 2
// 134.018 us; speedup vs baseline: 2.9343x; 2.9343x over previous
//
#include <hip/hip_runtime.h>
#include <hip/hip_bf16.h>

// ConvDeepSet via MFMA:
//   per batch b: V[m,c] = sum_n exp(fc*(x_n - y_m)^2) * co[n,c]   (bf16 MFMA, 32x32x16)
//   dens[m]     = sum_n K[m,n]                                    (fp32 VALU, exact)
//   out[m,b,r]  = bias[r] + W[r,0]*dens[m] + sum_c W[r,1+c]*(V[m,c]/(dens[m]+1e-8))
// Block: 256 thr = 4 waves, wave covers 32 m -> block 128 m. Grid 16*32 = 512 = 2 blocks/CU exactly.

#define N_CTX 2048
#define BATCH 16
#define M_TGT 4096
#define COUT  64
#define RDIM  128
#define TN    64
#define NTILES (N_CTX / TN)

typedef __attribute__((ext_vector_type(8)))  short        bf16x8;
typedef __attribute__((ext_vector_type(4)))  unsigned int uint4v;
typedef __attribute__((ext_vector_type(16))) float        floatx16;

#if __has_builtin(__builtin_amdgcn_exp2f)
#define EXP2F __builtin_amdgcn_exp2f
#else
#define EXP2F exp2f
#endif

static __device__ __forceinline__ unsigned int pack_bf16(float lo, float hi) {
    __hip_bfloat162 h = __float22bfloat162_rn(make_float2(lo, hi));
    return *reinterpret_cast<unsigned int*>(&h);
}
static __device__ __forceinline__ unsigned short f2bf(float f) {
    __hip_bfloat16 h = __float2bfloat16(f);
    return *reinterpret_cast<unsigned short*>(&h);
}

__global__ __launch_bounds__(256)
void convdeepset_mfma(const float* __restrict__ ci, const float* __restrict__ co,
                      const float* __restrict__ ti, const float* __restrict__ ls,
                      const float* __restrict__ W,  const float* __restrict__ bias,
                      float* __restrict__ out)
{
    // chunk-interleaved layouts: elem(c-major tile) = ch*512 + c*8 + (n&7), ch = n>>3
    __shared__ unsigned short co_t[4096];        //  8 KB  co tile, bf16, [ch][c][8n]
    __shared__ unsigned short wt[8192];          // 16 KB  W[:,1:65] bf16, [ch][r][8c]
    __shared__ unsigned short vstage[4 * 2048];  // 16 KB  per-wave V, [ch][m][8c]
    __shared__ float x_t[TN];                    // 256 B
    __shared__ float w0l[RDIM];                  // 512 B  W[:,0] fp32
    __shared__ float biasl[RDIM];                // 512 B

    const int tid  = threadIdx.x;
    const int lane = tid & 63;
    const int wv   = tid >> 6;
    const int g    = lane >> 5;       // MFMA k-group
    const int l31  = lane & 31;
    const int b    = blockIdx.x >> 5; // 0..15
    const int mt   = blockIdx.x & 31; // 0..31

    // ---- one-time staging: Wt (channels 1..64 -> bf16), w0, bias ----
    for (int e = tid; e < 4096; e += 256) {      // e = bf16-pair index
        const int ch  = e >> 9;                  // 0..7
        const int rem = e & 511;
        const int r   = rem >> 2;                // 0..127
        const int tp  = (rem & 3) << 1;          // 0,2,4,6
        const float f0 = W[r * 65 + 1 + ch * 8 + tp];
        const float f1 = W[r * 65 + 2 + ch * 8 + tp];
        *reinterpret_cast<unsigned int*>(&wt[ch * 1024 + r * 8 + tp]) = pack_bf16(f0, f1);
    }
    if (tid < RDIM) { w0l[tid] = W[tid * 65]; biasl[tid] = bias[tid]; }

    const int m0    = mt * 128 + wv * 32;        // wave's first m
    const float y   = ti[(size_t)(m0 + l31) * BATCH + b];
    const float lsv = ls[0];
    const float fc2 = (-0.5f / (lsv * lsv)) * 1.4426950408889634f;  // exp2 scale

    // staging coords: thread -> (c = tid&63, n-range base sn)
    const int sc = tid & 63;
    const int sn = (tid >> 6) * 16;
    const float* cob = co + (size_t)b * COUT + sc;   // co[n][b][c], n-stride 1024

    // prefetch tile 0 into registers
    float pf[16];
#pragma unroll
    for (int q = 0; q < 8; ++q) {
        pf[2*q]   = cob[(size_t)(sn + 2*q)     * (BATCH * COUT)];
        pf[2*q+1] = cob[(size_t)(sn + 2*q + 1) * (BATCH * COUT)];
    }
    float xpf = (tid < TN) ? ci[(size_t)tid * BATCH + b] : 0.0f;

    floatx16 acc0, acc1;
#pragma unroll
    for (int i = 0; i < 16; ++i) { acc0[i] = 0.0f; acc1[i] = 0.0f; }
    float dens = 0.0f;

    for (int t = 0; t < NTILES; ++t) {
        __syncthreads();                         // protect co_t/x_t from prev tile's readers
        // write prefetched co -> LDS (bf16 pairs along n; transpose to c-major chunks)
#pragma unroll
        for (int q = 0; q < 8; ++q) {
            const int noff = sn + 2*q;
            *reinterpret_cast<unsigned int*>(&co_t[(noff >> 3) * 512 + sc * 8 + (noff & 7)])
                = pack_bf16(pf[2*q], pf[2*q+1]);
        }
        if (tid < TN) x_t[tid] = xpf;
        __syncthreads();
        // prefetch next tile (hides L2 latency under compute)
        if (t + 1 < NTILES) {
            const int n0n = (t + 1) * TN;
#pragma unroll
            for (int q = 0; q < 8; ++q) {
                pf[2*q]   = cob[(size_t)(n0n + sn + 2*q)     * (BATCH * COUT)];
                pf[2*q+1] = cob[(size_t)(n0n + sn + 2*q + 1) * (BATCH * COUT)];
            }
            if (tid < TN) xpf = ci[(size_t)(n0n + tid) * BATCH + b];
        }
        // 4 k-steps of 16: K generated in-register directly in A-fragment layout
#pragma unroll
        for (int s = 0; s < 4; ++s) {
            const float* xp = &x_t[s * 16 + g * 8];
            const float4 xa = *(const float4*)(xp);
            const float4 xb = *(const float4*)(xp + 4);
            const float xs[8] = {xa.x, xa.y, xa.z, xa.w, xb.x, xb.y, xb.z, xb.w};
            float kv[8];
#pragma unroll
            for (int j = 0; j < 8; ++j) {
                const float d = xs[j] - y;
                kv[j] = EXP2F(fc2 * d * d);
                dens += kv[j];                   // density stays fp32
            }
            uint4v aw;
#pragma unroll
            for (int q = 0; q < 4; ++q) aw[q] = pack_bf16(kv[2*q], kv[2*q+1]);
            const bf16x8 av = __builtin_bit_cast(bf16x8, aw);
            const int ch = 2 * s + g;
            const bf16x8 b0 = *reinterpret_cast<const bf16x8*>(&co_t[ch * 512 + l31 * 8]);
            const bf16x8 b1 = *reinterpret_cast<const bf16x8*>(&co_t[ch * 512 + l31 * 8 + 256]);
            acc0 = __builtin_amdgcn_mfma_f32_32x32x16_bf16(av, b0, acc0, 0, 0, 0);
            acc1 = __builtin_amdgcn_mfma_f32_32x32x16_bf16(av, b1, acc1, 0, 0, 0);
        }
    }

    // complete density (lane g=0 covers n%16 in 0..7, g=1 covers 8..15; same m at lane^32)
    dens += __shfl_xor(dens, 32);

    // normalize channels, stage V (bf16, A-layout) to per-wave LDS region
    float drow[16];
    unsigned short* vs = vstage + wv * 2048;
#pragma unroll
    for (int reg = 0; reg < 16; ++reg) {
        const int row = (reg & 3) + 8 * (reg >> 2) + 4 * g;   // verified 32x32 C/D layout
        const float dr = __shfl(dens, row);                   // lane 'row' holds dens[m=row]
        drow[reg] = dr;
        const float dinv = 1.0f / (dr + 1e-8f);
        const float v0 = acc0[reg] * dinv;                    // c = l31
        const float v1 = acc1[reg] * dinv;                    // c = 32 + l31
        const int c0 = l31, c1 = 32 + l31;
        vs[(c0 >> 3) * 256 + row * 8 + (c0 & 7)] = f2bf(v0);
        vs[(c1 >> 3) * 256 + row * 8 + (c1 & 7)] = f2bf(v1);
    }

    // projection GEMM: D2[32 m][128 r] = V[32 m][64 c] * Wt[64 c][128 r]  (same-wave LDS, no barrier)
    floatx16 pacc[4];
#pragma unroll
    for (int rt = 0; rt < 4; ++rt)
#pragma unroll
        for (int i = 0; i < 16; ++i) pacc[rt][i] = 0.0f;

#pragma unroll
    for (int s2 = 0; s2 < 4; ++s2) {
        const int ch = 2 * s2 + g;
        const bf16x8 avp = *reinterpret_cast<const bf16x8*>(&vs[ch * 256 + l31 * 8]);
#pragma unroll
        for (int rt = 0; rt < 4; ++rt) {
            const bf16x8 bvp = *reinterpret_cast<const bf16x8*>(&wt[ch * 1024 + (rt * 32 + l31) * 8]);
            pacc[rt] = __builtin_amdgcn_mfma_f32_32x32x16_bf16(avp, bvp, pacc[rt], 0, 0, 0);
        }
    }

    // epilogue: fp32 density term + bias, coalesced stores
#pragma unroll
    for (int rt = 0; rt < 4; ++rt) {
        const int r = rt * 32 + l31;
        const float w0v = w0l[r];
        const float bv  = biasl[r];
#pragma unroll
        for (int reg = 0; reg < 16; ++reg) {
            const int row = (reg & 3) + 8 * (reg >> 2) + 4 * g;
            const float val = pacc[rt][reg] + drow[reg] * w0v + bv;
            out[((size_t)(m0 + row) * BATCH + b) * RDIM + r] = val;
        }
    }
}

extern "C" void kernel_launch(void* const* d_in, const int* in_sizes, int n_in,
                              void* d_out, int out_size, void* d_ws, size_t ws_size,
                              hipStream_t stream) {
    const float* ci   = (const float*)d_in[0];  // context_in  (N,B,1)
    const float* co   = (const float*)d_in[1];  // context_out (N,B,64)
    const float* ti   = (const float*)d_in[2];  // target_in   (M,B,1)
    const float* ls   = (const float*)d_in[3];  // lengthscale (1,)
    const float* W    = (const float*)d_in[4];  // (128,65)
    const float* bias = (const float*)d_in[5];  // (128,)
    float* o = (float*)d_out;                   // (M,B,128)
    (void)in_sizes; (void)n_in; (void)out_size; (void)d_ws; (void)ws_size;

    const int grid = BATCH * (M_TGT / 128);     // 16 * 32 = 512 blocks (2/CU exactly)
    convdeepset_mfma<<<grid, 256, 0, stream>>>(ci, co, ti, ls, W, bias, o);
}